// Round 8
// baseline (234.884 us; speedup 1.0000x reference)
//
#include <hip/hip_runtime.h>
#include <stdint.h>

typedef unsigned short ushort_t;
typedef __attribute__((ext_vector_type(4))) unsigned short ushort4_t;
typedef __attribute__((ext_vector_type(8))) short short8;
typedef __attribute__((ext_vector_type(4))) float float4_t;

#define AS1 __attribute__((address_space(1)))
#define AS3 __attribute__((address_space(3)))

__device__ inline ushort_t f2bf(float f) {
    unsigned x = __builtin_bit_cast(unsigned, f);
    unsigned r = x + 0x7fffu + ((x >> 16) & 1u);
    return (ushort_t)(r >> 16);
}
__device__ inline ushort_t f2bf_trunc(float f) {
    return (ushort_t)(__builtin_bit_cast(unsigned, f) >> 16);
}

// ---------- fused prep: transpose W_qkv, transpose W_proj, convert x ----------
// blocks [0,768): wqkv 1024x3072 -> T; [768,1024): wproj 1024x1024 -> T;
// [1024,3072): x fp32 -> bf16
__global__ __launch_bounds__(256) void prep_fused(
    const float* __restrict__ wqkv, const float* __restrict__ wproj,
    const float* __restrict__ x,
    ushort_t* __restrict__ wqkvT, ushort_t* __restrict__ wprojT,
    ushort_t* __restrict__ xbf) {
    __shared__ __align__(16) ushort_t tile[64][65];
    int bid = blockIdx.x, t = threadIdx.x;
    if (bid < 1024) {
        const float* in; ushort_t* out; int R, C, bx, by;
        if (bid < 768) { in = wqkv; out = wqkvT; R = 1024; C = 3072; bx = bid % 48; by = bid / 48; }
        else { int b2 = bid - 768; in = wproj; out = wprojT; R = 1024; C = 1024; bx = b2 % 16; by = b2 / 16; }
        int c0 = bx * 64, r0 = by * 64;
        for (int i = 0; i < 16; i++) {
            int idx = t + i * 256;
            int lr = idx >> 6, lc = idx & 63;
            tile[lr][lc] = f2bf(in[(size_t)(r0 + lr) * C + c0 + lc]);
        }
        __syncthreads();
        for (int i = 0; i < 16; i++) {
            int idx = t + i * 256;
            int lr = idx >> 6, lc = idx & 63;
            out[(size_t)(c0 + lr) * R + r0 + lc] = tile[lc][lr];
        }
    } else {
        size_t i = ((size_t)(bid - 1024) * 256 + t) * 8;
        float4_t a = *(const float4_t*)(x + i);
        float4_t b = *(const float4_t*)(x + i + 4);
        ushort_t u[8];
        u[0] = f2bf(a.x); u[1] = f2bf(a.y); u[2] = f2bf(a.z); u[3] = f2bf(a.w);
        u[4] = f2bf(b.x); u[5] = f2bf(b.y); u[6] = f2bf(b.z); u[7] = f2bf(b.w);
        *(ushort4_t*)(xbf + i) = *(ushort4_t*)&u[0];
        *(ushort4_t*)(xbf + i + 4) = *(ushort4_t*)&u[4];
    }
}

// ---------- zero-fill Oacc (4M floats in d_out) + lacc (64K floats) ----------
__global__ __launch_bounds__(256) void zero_acc(float4_t* __restrict__ Oacc,
                                                float4_t* __restrict__ lacc) {
    int bid = blockIdx.x, t = threadIdx.x;
    float4_t z = (float4_t){0.f, 0.f, 0.f, 0.f};
    if (bid < 1024) {
        size_t i = (size_t)bid * 256 + t;
        Oacc[i] = z; Oacc[i + 262144] = z; Oacc[i + 524288] = z; Oacc[i + 786432] = z;
    } else {
        size_t i = (size_t)(bid - 1024) * 256 + t;
        lacc[i] = z; lacc[i + 4096] = z; lacc[i + 8192] = z; lacc[i + 12288] = z;
    }
}

// ---------- GEMM1: q/k/v = xbf @ wqkvT^T, scatter to [b,h,n,d] ----------
__global__ __launch_bounds__(256) void gemm_qkv(
    const ushort_t* __restrict__ A, const ushort_t* __restrict__ Bt,
    ushort_t* __restrict__ outQ, ushort_t* __restrict__ outK, ushort_t* __restrict__ outV) {
    const int K = 1024;
    __shared__ __align__(16) ushort_t As[128 * 64];
    __shared__ __align__(16) ushort_t Bs[128 * 64];
    int t = threadIdx.x;
    int w = t >> 6, lane = t & 63;
    int quad = lane >> 4, l15 = lane & 15;
    int wM = w >> 1, wN = w & 1;
    int tM = blockIdx.y * 128, tN = blockIdx.x * 128;

    float4_t acc[4][4];
    for (int i = 0; i < 4; i++)
        for (int j = 0; j < 4; j++) acc[i][j] = (float4_t){0.f, 0.f, 0.f, 0.f};

    int lrow = lane >> 3;
    int lcol8 = (lane & 7) * 8;

    const ushort_t* Abase = A + (size_t)(tM + w * 32) * K;
    const ushort_t* Bbase = Bt + (size_t)(tN + w * 32) * K;

    for (int k0 = 0; k0 < K; k0 += 64) {
        __syncthreads();
        for (int i = 0; i < 4; i++) {
            const ushort_t* ga = Abase + (size_t)(i * 8 + lrow) * K + k0 + lcol8;
            __builtin_amdgcn_global_load_lds((AS1 void*)ga, (AS3 void*)&As[(w * 32 + i * 8) * 64], 16, 0, 0);
            const ushort_t* gb = Bbase + (size_t)(i * 8 + lrow) * K + k0 + lcol8;
            __builtin_amdgcn_global_load_lds((AS1 void*)gb, (AS3 void*)&Bs[(w * 32 + i * 8) * 64], 16, 0, 0);
        }
        __syncthreads();
        for (int kt = 0; kt < 2; kt++) {
            short8 af[4], bf[4];
            for (int m = 0; m < 4; m++)
                af[m] = *(const short8*)&As[(wM * 64 + m * 16 + l15) * 64 + kt * 32 + quad * 8];
            for (int n = 0; n < 4; n++)
                bf[n] = *(const short8*)&Bs[(wN * 64 + n * 16 + l15) * 64 + kt * 32 + quad * 8];
            for (int m = 0; m < 4; m++)
                for (int n = 0; n < 4; n++)
                    acc[m][n] = __builtin_amdgcn_mfma_f32_16x16x32_bf16(af[m], bf[n], acc[m][n], 0, 0, 0);
        }
    }

    for (int m = 0; m < 4; m++) {
        int gm = tM + wM * 64 + m * 16 + quad * 4;
        for (int n = 0; n < 4; n++) {
            int gn = tN + wN * 64 + n * 16 + l15;
            int three = gn >> 10;
            int h = (gn >> 6) & 15;
            int dd = gn & 63;
            ushort_t* dst = (three == 0) ? outQ : (three == 1) ? outK : outV;
            for (int r = 0; r < 4; r++) {
                int row = gm + r;
                int b = row >> 11;
                int ns = row & 2047;
                dst[(((size_t)(b * 16 + h) * 2048 + ns) << 6) + dd] = f2bf(acc[m][n][r]);
            }
        }
    }
}

// ---------- flash attention: paired q-tiles, deferred softmax, key-split z=2 ----------
// q,k,v: [BH][N][d] bf16. Partials: Oacc fp32 [bh][n][64], lacc fp32 [bh][n] (atomicAdd).
__global__ __launch_bounds__(256) void attn_kernel(
    const ushort_t* __restrict__ q, const ushort_t* __restrict__ k,
    const ushort_t* __restrict__ v, const int* __restrict__ pad,
    const int* __restrict__ csp, float* __restrict__ Oacc, float* __restrict__ lacc) {
    __shared__ __align__(16) ushort_t Ks[64 * 64];       // [key][dd], XOR-swizzled
    __shared__ __align__(16) ushort_t VsT[64 * 64];      // [dd][key], XOR-swizzled
    __shared__ __align__(16) ushort_t Ps[4][2][16 * 64]; // per-wave, per-tile
    __shared__ float padb[2048];

    int cs = csp[0];
    int t = threadIdx.x, w = t >> 6, lane = t & 63;
    int quad = lane >> 4, l15 = lane & 15;
    int bh = blockIdx.y;
    int b = bh >> 4;
    int xp = blockIdx.x;
    int z = blockIdx.z;            // key-split: tiles it ≡ z (mod 2)
    int qtA = 31 - xp, qtB = xp;
    int q0A = qtA * 64, q0B = qtB * 64;
    const float c1 = 0.18033688f;    // 0.125 * log2(e)
    const float c2 = -11.541560f;    // -8 * log2(e)

    for (int i = 0; i < 8; i++) {
        int key = t + i * 256;
        padb[key] = pad[b * 2048 + key] ? -1e38f : c2;
    }

    const ushort_t* qbA = q + ((size_t)bh * 2048 + q0A + w * 16 + l15) * 64;
    short8 qA0 = *(const short8*)(qbA + quad * 8);
    short8 qA1 = *(const short8*)(qbA + 32 + quad * 8);
    const ushort_t* qbB = q + ((size_t)bh * 2048 + q0B + w * 16 + l15) * 64;
    short8 qB0 = *(const short8*)(qbB + quad * 8);
    short8 qB1 = *(const short8*)(qbB + 32 + quad * 8);

    float4_t OA[4], OB[4];
    for (int i = 0; i < 4; i++) { OA[i] = (float4_t){0.f,0.f,0.f,0.f}; OB[i] = (float4_t){0.f,0.f,0.f,0.f}; }
    float lsA[4] = {0.f,0.f,0.f,0.f}, lsB[4] = {0.f,0.f,0.f,0.f};

    int csT = (cs + 63) >> 6;
    int nTA = qtA + 1; if (csT > nTA) nTA = csT;
    int nTB = qtB + 1; if (csT > nTB) nTB = csT;
    int nTmax = nTA > nTB ? nTA : nTB;

    const ushort_t* kbase = k + (size_t)bh * 2048 * 64;
    const ushort_t* vbase = v + (size_t)bh * 2048 * 64;

    int lrow = lane >> 3, lblk = lane & 7;
    int prowA = q0A + w * 16 + quad * 4;
    int prowB = q0B + w * 16 + quad * 4;
    int sw = l15 & 7;

    short8 vr0, vr1;
    auto loadV = [&](int it) {
        const ushort_t* vb = vbase + (size_t)(it * 64 + lane) * 64;
        vr0 = *(const short8*)(vb + w * 8);
        vr1 = *(const short8*)(vb + (w + 4) * 8);
    };
    if (z < nTmax) loadV(z);

    for (int it = z; it < nTmax; it += 2) {
        int k0 = it * 64;
        __syncthreads();  // previous compute done; LDS reusable
        for (int j = 0; j < 8; j++) {
            int sl = (((lane >> 3) ^ j) * 8) + (lane & 7);
            VsT[(w * 8 + j) * 64 + sl] = (ushort_t)vr0[j];
            VsT[((w + 4) * 8 + j) * 64 + sl] = (ushort_t)vr1[j];
        }
        for (int i = 0; i < 2; i++) {
            int brow = w * 16 + i * 8;
            const ushort_t* gk = kbase + (size_t)(k0 + brow + lrow) * 64 + ((lblk ^ lrow) * 8);
            __builtin_amdgcn_global_load_lds((AS1 void*)gk, (AS3 void*)&Ks[brow * 64], 16, 0, 0);
        }
        __syncthreads();  // K staged, VsT visible
        if (it + 2 < nTmax) loadV(it + 2);  // V prefetch overlaps compute

        bool actA = it < nTA, actB = it < nTB;

        short8 kf0[4], kf1[4];
        for (int ks = 0; ks < 4; ks++) {
            const ushort_t* krow = &Ks[(ks * 16 + l15) * 64];
            kf0[ks] = *(const short8*)(krow + (quad ^ sw) * 8);
            kf1[ks] = *(const short8*)(krow + ((4 + quad) ^ sw) * 8);
        }

        if (actA) {
            float4_t s[4];
            for (int ks = 0; ks < 4; ks++) {
                float4_t a = (float4_t){0.f,0.f,0.f,0.f};
                a = __builtin_amdgcn_mfma_f32_16x16x32_bf16(qA0, kf0[ks], a, 0, 0, 0);
                a = __builtin_amdgcn_mfma_f32_16x16x32_bf16(qA1, kf1[ks], a, 0, 0, 0);
                s[ks] = a;
            }
            bool needC = (it >= qtA) && (k0 + 63 >= cs);
            for (int ks = 0; ks < 4; ks++) {
                int key = k0 + ks * 16 + l15;
                float add = padb[key];
                for (int r = 0; r < 4; r++) {
                    float arg = s[ks][r] * c1 + add;
                    if (needC && (key > prowA + r) && (key >= cs)) arg = -1e38f;
                    float p = __builtin_amdgcn_exp2f(arg);
                    lsA[r] += p;
                    int row = quad * 4 + r;
                    Ps[w][0][row * 64 + (((ks * 2 + (l15 >> 3)) ^ (row & 7)) * 8) + (l15 & 7)] = f2bf_trunc(p);
                }
            }
        }
        if (actB) {
            float4_t s[4];
            for (int ks = 0; ks < 4; ks++) {
                float4_t a = (float4_t){0.f,0.f,0.f,0.f};
                a = __builtin_amdgcn_mfma_f32_16x16x32_bf16(qB0, kf0[ks], a, 0, 0, 0);
                a = __builtin_amdgcn_mfma_f32_16x16x32_bf16(qB1, kf1[ks], a, 0, 0, 0);
                s[ks] = a;
            }
            bool needC = (it >= qtB) && (k0 + 63 >= cs);
            for (int ks = 0; ks < 4; ks++) {
                int key = k0 + ks * 16 + l15;
                float add = padb[key];
                for (int r = 0; r < 4; r++) {
                    float arg = s[ks][r] * c1 + add;
                    if (needC && (key > prowB + r) && (key >= cs)) arg = -1e38f;
                    float p = __builtin_amdgcn_exp2f(arg);
                    lsB[r] += p;
                    int row = quad * 4 + r;
                    Ps[w][1][row * 64 + (((ks * 2 + (l15 >> 3)) ^ (row & 7)) * 8) + (l15 & 7)] = f2bf_trunc(p);
                }
            }
        }

        short8 vf0[4], vf1[4];
        for (int n = 0; n < 4; n++) {
            const ushort_t* vrow = &VsT[(n * 16 + l15) * 64];
            vf0[n] = *(const short8*)(vrow + (quad ^ sw) * 8);
            vf1[n] = *(const short8*)(vrow + ((4 + quad) ^ sw) * 8);
        }
        if (actA) {
            const ushort_t* prl = &Ps[w][0][l15 * 64];
            short8 pf0 = *(const short8*)(prl + (quad ^ sw) * 8);
            short8 pf1 = *(const short8*)(prl + ((4 + quad) ^ sw) * 8);
            for (int n = 0; n < 4; n++) {
                OA[n] = __builtin_amdgcn_mfma_f32_16x16x32_bf16(pf0, vf0[n], OA[n], 0, 0, 0);
                OA[n] = __builtin_amdgcn_mfma_f32_16x16x32_bf16(pf1, vf1[n], OA[n], 0, 0, 0);
            }
        }
        if (actB) {
            const ushort_t* prl = &Ps[w][1][l15 * 64];
            short8 pf0 = *(const short8*)(prl + (quad ^ sw) * 8);
            short8 pf1 = *(const short8*)(prl + ((4 + quad) ^ sw) * 8);
            for (int n = 0; n < 4; n++) {
                OB[n] = __builtin_amdgcn_mfma_f32_16x16x32_bf16(pf0, vf0[n], OB[n], 0, 0, 0);
                OB[n] = __builtin_amdgcn_mfma_f32_16x16x32_bf16(pf1, vf1[n], OB[n], 0, 0, 0);
            }
        }
    }

    // atomic partial reduction to Oacc / lacc
    for (int r = 0; r < 4; r++) {
        float l = lsA[r];
        l += __shfl_xor(l, 1, 64); l += __shfl_xor(l, 2, 64);
        l += __shfl_xor(l, 4, 64); l += __shfl_xor(l, 8, 64);
        int row = q0A + w * 16 + quad * 4 + r;
        if (l15 == 0) atomicAdd(&lacc[bh * 2048 + row], l);
        size_t ob = ((size_t)bh * 2048 + row) * 64;
        for (int n = 0; n < 4; n++)
            atomicAdd(&Oacc[ob + n * 16 + l15], OA[n][r]);
    }
    for (int r = 0; r < 4; r++) {
        float l = lsB[r];
        l += __shfl_xor(l, 1, 64); l += __shfl_xor(l, 2, 64);
        l += __shfl_xor(l, 4, 64); l += __shfl_xor(l, 8, 64);
        int row = q0B + w * 16 + quad * 4 + r;
        if (l15 == 0) atomicAdd(&lacc[bh * 2048 + row], l);
        size_t ob = ((size_t)bh * 2048 + row) * 64;
        for (int n = 0; n < 4; n++)
            atomicAdd(&Oacc[ob + n * 16 + l15], OB[n][r]);
    }
}

// ---------- GEMM2: out = (Oacc/l) @ wprojT^T + bias (1/l applied in A-staging) ----------
// A logical [4096][1024]: row=(b,n), col=(h,dd) -> Oacc[((b*16+h)*2048+n)*64+dd]
__global__ __launch_bounds__(256) void gemm_out(
    const float* __restrict__ Oacc, const float* __restrict__ lacc,
    const ushort_t* __restrict__ Bt, const float* __restrict__ bias,
    float* __restrict__ outC) {
    const int K = 1024, N = 1024;
    __shared__ __align__(16) ushort_t As[128 * 64];
    __shared__ __align__(16) ushort_t Bs[128 * 64];
    int t = threadIdx.x;
    int w = t >> 6, lane = t & 63;
    int quad = lane >> 4, l15 = lane & 15;
    int wM = w >> 1, wN = w & 1;
    int tM = blockIdx.y * 128, tN = blockIdx.x * 128;

    float4_t acc[4][4];
    for (int i = 0; i < 4; i++)
        for (int j = 0; j < 4; j++) acc[i][j] = (float4_t){0.f, 0.f, 0.f, 0.f};

    int lrow = lane >> 3;
    int lcol8 = (lane & 7) * 8;
    const ushort_t* Bbase = Bt + (size_t)(tN + w * 32) * K;

    for (int k0 = 0; k0 < K; k0 += 64) {
        int h = k0 >> 6;
        __syncthreads();
        // A-stage: fp32 Oacc, scale by 1/l (per head-row), convert to bf16
        for (int i = 0; i < 8; i++) {
            int e = t + i * 256;
            int row = e >> 4, c4 = (e & 15) * 4;
            int gm = tM + row;
            int b = gm >> 11, n = gm & 2047;
            size_t base = ((size_t)(b * 16 + h) * 2048 + n) * 64;
            float l = lacc[(b * 16 + h) * 2048 + n];
            float inv = l > 0.f ? __builtin_amdgcn_rcpf(l) : 0.f;
            float4_t f = *(const float4_t*)&Oacc[base + c4];
            ushort4_t u;
            u.x = f2bf(f.x * inv); u.y = f2bf(f.y * inv);
            u.z = f2bf(f.z * inv); u.w = f2bf(f.w * inv);
            *(ushort4_t*)&As[row * 64 + c4] = u;
        }
        for (int i = 0; i < 4; i++) {
            const ushort_t* gb = Bbase + (size_t)(i * 8 + lrow) * K + k0 + lcol8;
            __builtin_amdgcn_global_load_lds((AS1 void*)gb, (AS3 void*)&Bs[(w * 32 + i * 8) * 64], 16, 0, 0);
        }
        __syncthreads();
        for (int kt = 0; kt < 2; kt++) {
            short8 af[4], bf[4];
            for (int m = 0; m < 4; m++)
                af[m] = *(const short8*)&As[(wM * 64 + m * 16 + l15) * 64 + kt * 32 + quad * 8];
            for (int n = 0; n < 4; n++)
                bf[n] = *(const short8*)&Bs[(wN * 64 + n * 16 + l15) * 64 + kt * 32 + quad * 8];
            for (int m = 0; m < 4; m++)
                for (int n = 0; n < 4; n++)
                    acc[m][n] = __builtin_amdgcn_mfma_f32_16x16x32_bf16(af[m], bf[n], acc[m][n], 0, 0, 0);
        }
    }

    for (int m = 0; m < 4; m++) {
        int gm = tM + wM * 64 + m * 16 + quad * 4;
        for (int n = 0; n < 4; n++) {
            int gn = tN + wN * 64 + n * 16 + l15;
            float bv = bias[gn];
            for (int r = 0; r < 4; r++)
                outC[(size_t)(gm + r) * N + gn] = acc[m][n][r] + bv;
        }
    }
}

// ---------- coalesced 16 MB copy: tmp (ws) -> d_out ----------
__global__ __launch_bounds__(256) void copy_out(const float4_t* __restrict__ in,
                                                float4_t* __restrict__ out) {
    size_t i = (size_t)blockIdx.x * 256 + threadIdx.x;
    out[i] = in[i];
    out[i + 262144] = in[i + 262144];
    out[i + 524288] = in[i + 524288];
    out[i + 786432] = in[i + 786432];
}

extern "C" void kernel_launch(void* const* d_in, const int* in_sizes, int n_in,
                              void* d_out, int out_size, void* d_ws, size_t ws_size,
                              hipStream_t stream) {
    const float* x = (const float*)d_in[0];
    const int* pad = (const int*)d_in[1];
    const int* cs = (const int*)d_in[2];
    const float* wqkv = (const float*)d_in[3];
    const float* wproj = (const float*)d_in[4];
    const float* bproj = (const float*)d_in[5];
    float* out = (float*)d_out;

    // ws (peak 32 MB, all lifetimes audited):
    //   q[0,8M) k[8,16M) v[16,24M)            gemm1 -> attn
    //   wqkvT[24,30M)                         prep -> gemm1 (dies)
    //   wprojT[30,32M)                        prep -> gemm_out (never aliased)
    //   lacc fp32 [24,24.25M)                 zero -> gemm_out (over dead wqkvT)
    //   tmp fp32 [0,16M)                      gemm_out -> copy (over dead q,k)
    // d_out: xbf bf16 [0,8M) prep->gemm1; Oacc fp32 [0,16M) zero->gemm_out; final out.
    ushort_t* ws = (ushort_t*)d_ws;
    ushort_t* qws = ws;
    ushort_t* kws = ws + (size_t)4194304;
    ushort_t* vws = ws + (size_t)8388608;
    ushort_t* wqkvT = ws + (size_t)12582912;
    ushort_t* wprojT = ws + (size_t)15728640;
    float* lacc = (float*)((char*)d_ws + 25165824);
    float* tmp = (float*)d_ws;
    ushort_t* xbf = (ushort_t*)d_out;
    float* Oacc = (float*)d_out;

    prep_fused<<<3072, 256, 0, stream>>>(wqkv, wproj, x, wqkvT, wprojT, xbf);
    gemm_qkv<<<dim3(24, 32), 256, 0, stream>>>(xbf, wqkvT, qws, kws, vws);
    zero_acc<<<1040, 256, 0, stream>>>((float4_t*)Oacc, (float4_t*)lacc);
    attn_kernel<<<dim3(16, 32, 2), 256, 0, stream>>>(qws, kws, vws, pad, cs, Oacc, lacc);
    gemm_out<<<dim3(8, 32), 256, 0, stream>>>(Oacc, lacc, wprojT, bproj, tmp);
    copy_out<<<1024, 256, 0, stream>>>((const float4_t*)tmp, (float4_t*)d_out);
}

// Round 9
// 232.812 us; speedup vs baseline: 1.0089x; 1.0089x over previous
//
#include <hip/hip_runtime.h>
#include <stdint.h>

typedef unsigned short ushort_t;
typedef __attribute__((ext_vector_type(4))) unsigned short ushort4_t;
typedef __attribute__((ext_vector_type(8))) short short8;
typedef __attribute__((ext_vector_type(4))) float float4_t;

#define AS1 __attribute__((address_space(1)))
#define AS3 __attribute__((address_space(3)))

__device__ inline ushort_t f2bf(float f) {
    unsigned x = __builtin_bit_cast(unsigned, f);
    unsigned r = x + 0x7fffu + ((x >> 16) & 1u);
    return (ushort_t)(r >> 16);
}
__device__ inline ushort_t f2bf_trunc(float f) {
    return (ushort_t)(__builtin_bit_cast(unsigned, f) >> 16);
}

// ---------- fused prep: transpose W_qkv + convert x ----------
// blocks [0,768): wqkv 1024x3072 -> T bf16; [768,2816): x fp32 -> bf16
__global__ __launch_bounds__(256) void prep_fused(
    const float* __restrict__ wqkv, const float* __restrict__ x,
    ushort_t* __restrict__ wqkvT, ushort_t* __restrict__ xbf) {
    __shared__ __align__(16) ushort_t tile[64][65];
    int bid = blockIdx.x, t = threadIdx.x;
    if (bid < 768) {
        int bx = bid % 48, by = bid / 48;
        int c0 = bx * 64, r0 = by * 64;
        for (int i = 0; i < 16; i++) {
            int idx = t + i * 256;
            int lr = idx >> 6, lc = idx & 63;
            tile[lr][lc] = f2bf(wqkv[(size_t)(r0 + lr) * 3072 + c0 + lc]);
        }
        __syncthreads();
        for (int i = 0; i < 16; i++) {
            int idx = t + i * 256;
            int lr = idx >> 6, lc = idx & 63;
            wqkvT[(size_t)(c0 + lr) * 1024 + r0 + lc] = tile[lc][lr];
        }
    } else {
        size_t i = ((size_t)(bid - 768) * 256 + t) * 8;
        float4_t a = *(const float4_t*)(x + i);
        float4_t b = *(const float4_t*)(x + i + 4);
        ushort_t u[8];
        u[0] = f2bf(a.x); u[1] = f2bf(a.y); u[2] = f2bf(a.z); u[3] = f2bf(a.w);
        u[4] = f2bf(b.x); u[5] = f2bf(b.y); u[6] = f2bf(b.z); u[7] = f2bf(b.w);
        *(ushort4_t*)(xbf + i) = *(ushort4_t*)&u[0];
        *(ushort4_t*)(xbf + i + 4) = *(ushort4_t*)&u[4];
    }
}

// ---------- transpose+convert: in fp32 [R][C] -> out bf16 [C][R] ----------
__global__ __launch_bounds__(256) void transpose_f32_bf16(const float* __restrict__ in,
                                                          ushort_t* __restrict__ out,
                                                          int R, int C) {
    __shared__ __align__(16) ushort_t tile[64][65];
    int c0 = blockIdx.x * 64, r0 = blockIdx.y * 64;
    int t = threadIdx.x;
    for (int i = 0; i < 16; i++) {
        int idx = t + i * 256;
        int lr = idx >> 6, lc = idx & 63;
        tile[lr][lc] = f2bf(in[(size_t)(r0 + lr) * C + c0 + lc]);
    }
    __syncthreads();
    for (int i = 0; i < 16; i++) {
        int idx = t + i * 256;
        int lr = idx >> 6, lc = idx & 63;
        out[(size_t)(c0 + lr) * R + r0 + lc] = tile[lc][lr];
    }
}

// ---------- GEMM1: q/k/v = xbf @ wqkvT^T, scatter to [b,h,n,d] ----------
__global__ __launch_bounds__(256) void gemm_qkv(
    const ushort_t* __restrict__ A, const ushort_t* __restrict__ Bt,
    ushort_t* __restrict__ outQ, ushort_t* __restrict__ outK, ushort_t* __restrict__ outV) {
    const int K = 1024;
    __shared__ __align__(16) ushort_t As[128 * 64];
    __shared__ __align__(16) ushort_t Bs[128 * 64];
    int t = threadIdx.x;
    int w = t >> 6, lane = t & 63;
    int quad = lane >> 4, l15 = lane & 15;
    int wM = w >> 1, wN = w & 1;
    int tM = blockIdx.y * 128, tN = blockIdx.x * 128;

    float4_t acc[4][4];
    for (int i = 0; i < 4; i++)
        for (int j = 0; j < 4; j++) acc[i][j] = (float4_t){0.f, 0.f, 0.f, 0.f};

    int lrow = lane >> 3;
    int lcol8 = (lane & 7) * 8;

    const ushort_t* Abase = A + (size_t)(tM + w * 32) * K;
    const ushort_t* Bbase = Bt + (size_t)(tN + w * 32) * K;

    for (int k0 = 0; k0 < K; k0 += 64) {
        __syncthreads();
        for (int i = 0; i < 4; i++) {
            const ushort_t* ga = Abase + (size_t)(i * 8 + lrow) * K + k0 + lcol8;
            __builtin_amdgcn_global_load_lds((AS1 void*)ga, (AS3 void*)&As[(w * 32 + i * 8) * 64], 16, 0, 0);
            const ushort_t* gb = Bbase + (size_t)(i * 8 + lrow) * K + k0 + lcol8;
            __builtin_amdgcn_global_load_lds((AS1 void*)gb, (AS3 void*)&Bs[(w * 32 + i * 8) * 64], 16, 0, 0);
        }
        __syncthreads();
        for (int kt = 0; kt < 2; kt++) {
            short8 af[4], bf[4];
            for (int m = 0; m < 4; m++)
                af[m] = *(const short8*)&As[(wM * 64 + m * 16 + l15) * 64 + kt * 32 + quad * 8];
            for (int n = 0; n < 4; n++)
                bf[n] = *(const short8*)&Bs[(wN * 64 + n * 16 + l15) * 64 + kt * 32 + quad * 8];
            for (int m = 0; m < 4; m++)
                for (int n = 0; n < 4; n++)
                    acc[m][n] = __builtin_amdgcn_mfma_f32_16x16x32_bf16(af[m], bf[n], acc[m][n], 0, 0, 0);
        }
    }

    for (int m = 0; m < 4; m++) {
        int gm = tM + wM * 64 + m * 16 + quad * 4;
        for (int n = 0; n < 4; n++) {
            int gn = tN + wN * 64 + n * 16 + l15;
            int three = gn >> 10;
            int h = (gn >> 6) & 15;
            int dd = gn & 63;
            ushort_t* dst = (three == 0) ? outQ : (three == 1) ? outK : outV;
            for (int r = 0; r < 4; r++) {
                int row = gm + r;
                int b = row >> 11;
                int ns = row & 2047;
                dst[(((size_t)(b * 16 + h) * 2048 + ns) << 6) + dd] = f2bf(acc[m][n][r]);
            }
        }
    }
}

// ---------- flash attention: row-split paired q-tiles, deferred softmax ----------
// grid (16, 32, 2). z = row-half. Wave w<2 -> tile qtA rows z*32+w*16;
// w>=2 -> tile qtB rows z*32+(w-2)*16. Direct bf16 output (waves own full rows).
// LDS 32 KB -> 5 blocks/CU capacity; grid 1024 -> 4 blocks/CU.
__global__ __launch_bounds__(256) void attn_kernel(
    const ushort_t* __restrict__ q, const ushort_t* __restrict__ k,
    const ushort_t* __restrict__ v, const int* __restrict__ pad,
    const int* __restrict__ csp, ushort_t* __restrict__ out) {
    __shared__ __align__(16) ushort_t Ks[64 * 64];    // [key][dd], XOR-swizzled
    __shared__ __align__(16) ushort_t VsT[64 * 64];   // [dd][key], XOR-swizzled
    __shared__ __align__(16) ushort_t Ps[4][16 * 64]; // per-wave
    __shared__ float padb[2048];

    int cs = csp[0];
    int t = threadIdx.x, w = t >> 6, lane = t & 63;
    int quad = lane >> 4, l15 = lane & 15;
    int bh = blockIdx.y;
    int b = bh >> 4, h = bh & 15;
    int xp = blockIdx.x;
    int z = blockIdx.z;
    int qtA = 31 - xp, qtB = xp;           // qtA > qtB always (xp in [0,16))
    int myqt = (w < 2) ? qtA : qtB;
    int q0 = myqt * 64;
    int rbase = q0 + z * 32 + (w & 1) * 16;  // this wave's 16 q-rows
    const float c1 = 0.18033688f;    // 0.125 * log2(e)
    const float c2 = -11.541560f;    // -8 * log2(e)

    for (int i = 0; i < 8; i++) {
        int key = t + i * 256;
        padb[key] = pad[b * 2048 + key] ? -1e38f : c2;
    }

    const ushort_t* qb = q + ((size_t)bh * 2048 + rbase + l15) * 64;
    short8 qf0 = *(const short8*)(qb + quad * 8);
    short8 qf1 = *(const short8*)(qb + 32 + quad * 8);

    float4_t O[4];
    for (int i = 0; i < 4; i++) O[i] = (float4_t){0.f, 0.f, 0.f, 0.f};
    float ls[4] = {0.f, 0.f, 0.f, 0.f};

    int csT = (cs + 63) >> 6;
    int nTA = qtA + 1; if (csT > nTA) nTA = csT;
    int nTB = qtB + 1; if (csT > nTB) nTB = csT;
    int myNT = (w < 2) ? nTA : nTB;
    // loop bound = nTA (>= nTB since qtA > qtB)

    const ushort_t* kbase = k + (size_t)bh * 2048 * 64;
    const ushort_t* vbase = v + (size_t)bh * 2048 * 64;

    int lrow = lane >> 3, lblk = lane & 7;
    int prow = rbase + quad * 4;
    int sw = l15 & 7;

    short8 vr0, vr1;
    auto loadV = [&](int it) {
        const ushort_t* vb = vbase + (size_t)(it * 64 + lane) * 64;
        vr0 = *(const short8*)(vb + w * 8);
        vr1 = *(const short8*)(vb + (w + 4) * 8);
    };
    loadV(0);

    for (int it = 0; it < nTA; it++) {
        int k0 = it * 64;
        __syncthreads();  // previous compute done; LDS reusable
        // V^T from prefetched regs (swizzled b16 writes)
        for (int j = 0; j < 8; j++) {
            int sl = (((lane >> 3) ^ j) * 8) + (lane & 7);
            VsT[(w * 8 + j) * 64 + sl] = (ushort_t)vr0[j];
            VsT[((w + 4) * 8 + j) * 64 + sl] = (ushort_t)vr1[j];
        }
        // K tile via glds (source-XOR'd for swizzle)
        for (int i = 0; i < 2; i++) {
            int brow = w * 16 + i * 8;
            const ushort_t* gk = kbase + (size_t)(k0 + brow + lrow) * 64 + ((lblk ^ lrow) * 8);
            __builtin_amdgcn_global_load_lds((AS1 void*)gk, (AS3 void*)&Ks[brow * 64], 16, 0, 0);
        }
        __syncthreads();  // K staged, VsT visible
        if (it + 1 < nTA) loadV(it + 1);  // V prefetch overlaps compute

        if (it < myNT) {
            short8 kf0[4], kf1[4];
            for (int ks = 0; ks < 4; ks++) {
                const ushort_t* krow = &Ks[(ks * 16 + l15) * 64];
                kf0[ks] = *(const short8*)(krow + (quad ^ sw) * 8);
                kf1[ks] = *(const short8*)(krow + ((4 + quad) ^ sw) * 8);
            }
            float4_t s[4];
            for (int ks = 0; ks < 4; ks++) {
                float4_t a = (float4_t){0.f, 0.f, 0.f, 0.f};
                a = __builtin_amdgcn_mfma_f32_16x16x32_bf16(qf0, kf0[ks], a, 0, 0, 0);
                a = __builtin_amdgcn_mfma_f32_16x16x32_bf16(qf1, kf1[ks], a, 0, 0, 0);
                s[ks] = a;
            }
            bool needC = (it >= myqt) && (k0 + 63 >= cs);
            for (int ks = 0; ks < 4; ks++) {
                int key = k0 + ks * 16 + l15;
                float add = padb[key];
                for (int r = 0; r < 4; r++) {
                    float arg = s[ks][r] * c1 + add;
                    if (needC && (key > prow + r) && (key >= cs)) arg = -1e38f;
                    float p = __builtin_amdgcn_exp2f(arg);
                    ls[r] += p;
                    int row = quad * 4 + r;
                    Ps[w][row * 64 + (((ks * 2 + (l15 >> 3)) ^ (row & 7)) * 8) + (l15 & 7)] = f2bf_trunc(p);
                }
            }
            const ushort_t* prl = &Ps[w][l15 * 64];
            short8 pf0 = *(const short8*)(prl + (quad ^ sw) * 8);
            short8 pf1 = *(const short8*)(prl + ((4 + quad) ^ sw) * 8);
            for (int n = 0; n < 4; n++) {
                const ushort_t* vrow = &VsT[(n * 16 + l15) * 64];
                short8 vf0 = *(const short8*)(vrow + (quad ^ sw) * 8);
                short8 vf1 = *(const short8*)(vrow + ((4 + quad) ^ sw) * 8);
                O[n] = __builtin_amdgcn_mfma_f32_16x16x32_bf16(pf0, vf0, O[n], 0, 0, 0);
                O[n] = __builtin_amdgcn_mfma_f32_16x16x32_bf16(pf1, vf1, O[n], 0, 0, 0);
            }
        }
    }

    // l reduction across the 16 key-lanes, normalize, direct bf16 store
    for (int r = 0; r < 4; r++) {
        float l = ls[r];
        l += __shfl_xor(l, 1, 64); l += __shfl_xor(l, 2, 64);
        l += __shfl_xor(l, 4, 64); l += __shfl_xor(l, 8, 64);
        float inv = l > 0.f ? 1.f / l : 0.f;
        int row = rbase + quad * 4 + r;
        size_t ob = ((size_t)b * 2048 + row) * 1024 + h * 64;
        for (int n = 0; n < 4; n++)
            out[ob + n * 16 + l15] = f2bf(O[n][r] * inv);
    }
}

// ---------- GEMM2: out = ao @ wprojT^T + bias (bf16 A via glds, fp32 out) ----------
__global__ __launch_bounds__(256) void gemm_out_k(
    const ushort_t* __restrict__ A, const ushort_t* __restrict__ Bt,
    const float* __restrict__ bias, float* __restrict__ outC) {
    const int K = 1024, N = 1024;
    __shared__ __align__(16) ushort_t As[128 * 64];
    __shared__ __align__(16) ushort_t Bs[128 * 64];
    int t = threadIdx.x;
    int w = t >> 6, lane = t & 63;
    int quad = lane >> 4, l15 = lane & 15;
    int wM = w >> 1, wN = w & 1;
    int tM = blockIdx.y * 128, tN = blockIdx.x * 128;

    float4_t acc[4][4];
    for (int i = 0; i < 4; i++)
        for (int j = 0; j < 4; j++) acc[i][j] = (float4_t){0.f, 0.f, 0.f, 0.f};

    int lrow = lane >> 3;
    int lcol8 = (lane & 7) * 8;

    const ushort_t* Abase = A + (size_t)(tM + w * 32) * K;
    const ushort_t* Bbase = Bt + (size_t)(tN + w * 32) * K;

    for (int k0 = 0; k0 < K; k0 += 64) {
        __syncthreads();
        for (int i = 0; i < 4; i++) {
            const ushort_t* ga = Abase + (size_t)(i * 8 + lrow) * K + k0 + lcol8;
            __builtin_amdgcn_global_load_lds((AS1 void*)ga, (AS3 void*)&As[(w * 32 + i * 8) * 64], 16, 0, 0);
            const ushort_t* gb = Bbase + (size_t)(i * 8 + lrow) * K + k0 + lcol8;
            __builtin_amdgcn_global_load_lds((AS1 void*)gb, (AS3 void*)&Bs[(w * 32 + i * 8) * 64], 16, 0, 0);
        }
        __syncthreads();
        for (int kt = 0; kt < 2; kt++) {
            short8 af[4], bf[4];
            for (int m = 0; m < 4; m++)
                af[m] = *(const short8*)&As[(wM * 64 + m * 16 + l15) * 64 + kt * 32 + quad * 8];
            for (int n = 0; n < 4; n++)
                bf[n] = *(const short8*)&Bs[(wN * 64 + n * 16 + l15) * 64 + kt * 32 + quad * 8];
            for (int m = 0; m < 4; m++)
                for (int n = 0; n < 4; n++)
                    acc[m][n] = __builtin_amdgcn_mfma_f32_16x16x32_bf16(af[m], bf[n], acc[m][n], 0, 0, 0);
        }
    }

    for (int m = 0; m < 4; m++) {
        int gm = tM + wM * 64 + m * 16 + quad * 4;
        for (int n = 0; n < 4; n++) {
            int gn = tN + wN * 64 + n * 16 + l15;
            float bv = bias[gn];
            for (int r = 0; r < 4; r++)
                outC[(size_t)(gm + r) * N + gn] = acc[m][n][r] + bv;
        }
    }
}

extern "C" void kernel_launch(void* const* d_in, const int* in_sizes, int n_in,
                              void* d_out, int out_size, void* d_ws, size_t ws_size,
                              hipStream_t stream) {
    const float* x = (const float*)d_in[0];
    const int* pad = (const int*)d_in[1];
    const int* cs = (const int*)d_in[2];
    const float* wqkv = (const float*)d_in[3];
    const float* wproj = (const float*)d_in[4];
    const float* bproj = (const float*)d_in[5];
    float* out = (float*)d_out;

    // ws (peak 32 MB, lifetimes audited):
    //   q[0,8M) k[8,16M) v[16,24M)        gemm1 -> attn
    //   wqkvT[24,30M)                     prep -> gemm1 (dies)
    //   ao bf16 [24,32M)                  attn -> gemm2 (over dead wqkvT)
    //   wprojT[0,2M)                      transposed AFTER attn (over dead q)
    // d_out: xbf bf16 [0,8M) prep -> gemm1 (dies); final fp32 out from gemm2.
    ushort_t* ws = (ushort_t*)d_ws;
    ushort_t* qws = ws;
    ushort_t* kws = ws + (size_t)4194304;
    ushort_t* vws = ws + (size_t)8388608;
    ushort_t* wqkvT = ws + (size_t)12582912;
    ushort_t* aows = ws + (size_t)12582912;
    ushort_t* wprojT = ws;
    ushort_t* xbf = (ushort_t*)d_out;

    prep_fused<<<2816, 256, 0, stream>>>(wqkv, x, wqkvT, xbf);
    gemm_qkv<<<dim3(24, 32), 256, 0, stream>>>(xbf, wqkvT, qws, kws, vws);
    attn_kernel<<<dim3(16, 32, 2), 256, 0, stream>>>(qws, kws, vws, pad, cs, aows);
    transpose_f32_bf16<<<dim3(16, 16), 256, 0, stream>>>(wproj, wprojT, 1024, 1024);
    gemm_out_k<<<dim3(8, 32), 256, 0, stream>>>(aows, wprojT, bproj, out);
}

// Round 10
// 206.831 us; speedup vs baseline: 1.1356x; 1.1256x over previous
//
#include <hip/hip_runtime.h>
#include <stdint.h>

typedef unsigned short ushort_t;
typedef __attribute__((ext_vector_type(4))) unsigned short ushort4_t;
typedef __attribute__((ext_vector_type(8))) short short8;
typedef __attribute__((ext_vector_type(4))) float float4_t;

#define AS1 __attribute__((address_space(1)))
#define AS3 __attribute__((address_space(3)))

__device__ inline ushort_t f2bf(float f) {
    unsigned x = __builtin_bit_cast(unsigned, f);
    unsigned r = x + 0x7fffu + ((x >> 16) & 1u);
    return (ushort_t)(r >> 16);
}
__device__ inline ushort_t f2bf_trunc(float f) {
    return (ushort_t)(__builtin_bit_cast(unsigned, f) >> 16);
}

// ---------- fused prep: transpose W_qkv + convert x ----------
// blocks [0,768): wqkv 1024x3072 -> T bf16; [768,2816): x fp32 -> bf16
__global__ __launch_bounds__(256) void prep_fused(
    const float* __restrict__ wqkv, const float* __restrict__ x,
    ushort_t* __restrict__ wqkvT, ushort_t* __restrict__ xbf) {
    __shared__ __align__(16) ushort_t tile[64][65];
    int bid = blockIdx.x, t = threadIdx.x;
    if (bid < 768) {
        int bx = bid % 48, by = bid / 48;
        int c0 = bx * 64, r0 = by * 64;
        for (int i = 0; i < 16; i++) {
            int idx = t + i * 256;
            int lr = idx >> 6, lc = idx & 63;
            tile[lr][lc] = f2bf(wqkv[(size_t)(r0 + lr) * 3072 + c0 + lc]);
        }
        __syncthreads();
        for (int i = 0; i < 16; i++) {
            int idx = t + i * 256;
            int lr = idx >> 6, lc = idx & 63;
            wqkvT[(size_t)(c0 + lr) * 1024 + r0 + lc] = tile[lc][lr];
        }
    } else {
        size_t i = ((size_t)(bid - 768) * 256 + t) * 8;
        float4_t a = *(const float4_t*)(x + i);
        float4_t b = *(const float4_t*)(x + i + 4);
        ushort_t u[8];
        u[0] = f2bf(a.x); u[1] = f2bf(a.y); u[2] = f2bf(a.z); u[3] = f2bf(a.w);
        u[4] = f2bf(b.x); u[5] = f2bf(b.y); u[6] = f2bf(b.z); u[7] = f2bf(b.w);
        *(ushort4_t*)(xbf + i) = *(ushort4_t*)&u[0];
        *(ushort4_t*)(xbf + i + 4) = *(ushort4_t*)&u[4];
    }
}

// ---------- transpose+convert: in fp32 [R][C] -> out bf16 [C][R] ----------
__global__ __launch_bounds__(256) void transpose_f32_bf16(const float* __restrict__ in,
                                                          ushort_t* __restrict__ out,
                                                          int R, int C) {
    __shared__ __align__(16) ushort_t tile[64][65];
    int c0 = blockIdx.x * 64, r0 = blockIdx.y * 64;
    int t = threadIdx.x;
    for (int i = 0; i < 16; i++) {
        int idx = t + i * 256;
        int lr = idx >> 6, lc = idx & 63;
        tile[lr][lc] = f2bf(in[(size_t)(r0 + lr) * C + c0 + lc]);
    }
    __syncthreads();
    for (int i = 0; i < 16; i++) {
        int idx = t + i * 256;
        int lr = idx >> 6, lc = idx & 63;
        out[(size_t)(c0 + lr) * R + r0 + lc] = tile[lc][lr];
    }
}

// ---------- GEMM1: q/k/v = xbf @ wqkvT^T, scatter to [b,h,n,d] ----------
__global__ __launch_bounds__(256) void gemm_qkv(
    const ushort_t* __restrict__ A, const ushort_t* __restrict__ Bt,
    ushort_t* __restrict__ outQ, ushort_t* __restrict__ outK, ushort_t* __restrict__ outV) {
    const int K = 1024;
    __shared__ __align__(16) ushort_t As[128 * 64];
    __shared__ __align__(16) ushort_t Bs[128 * 64];
    int t = threadIdx.x;
    int w = t >> 6, lane = t & 63;
    int quad = lane >> 4, l15 = lane & 15;
    int wM = w >> 1, wN = w & 1;
    int tM = blockIdx.y * 128, tN = blockIdx.x * 128;

    float4_t acc[4][4];
    for (int i = 0; i < 4; i++)
        for (int j = 0; j < 4; j++) acc[i][j] = (float4_t){0.f, 0.f, 0.f, 0.f};

    int lrow = lane >> 3;
    int lcol8 = (lane & 7) * 8;

    const ushort_t* Abase = A + (size_t)(tM + w * 32) * K;
    const ushort_t* Bbase = Bt + (size_t)(tN + w * 32) * K;

    for (int k0 = 0; k0 < K; k0 += 64) {
        __syncthreads();
        for (int i = 0; i < 4; i++) {
            const ushort_t* ga = Abase + (size_t)(i * 8 + lrow) * K + k0 + lcol8;
            __builtin_amdgcn_global_load_lds((AS1 void*)ga, (AS3 void*)&As[(w * 32 + i * 8) * 64], 16, 0, 0);
            const ushort_t* gb = Bbase + (size_t)(i * 8 + lrow) * K + k0 + lcol8;
            __builtin_amdgcn_global_load_lds((AS1 void*)gb, (AS3 void*)&Bs[(w * 32 + i * 8) * 64], 16, 0, 0);
        }
        __syncthreads();
        for (int kt = 0; kt < 2; kt++) {
            short8 af[4], bf[4];
            for (int m = 0; m < 4; m++)
                af[m] = *(const short8*)&As[(wM * 64 + m * 16 + l15) * 64 + kt * 32 + quad * 8];
            for (int n = 0; n < 4; n++)
                bf[n] = *(const short8*)&Bs[(wN * 64 + n * 16 + l15) * 64 + kt * 32 + quad * 8];
            for (int m = 0; m < 4; m++)
                for (int n = 0; n < 4; n++)
                    acc[m][n] = __builtin_amdgcn_mfma_f32_16x16x32_bf16(af[m], bf[n], acc[m][n], 0, 0, 0);
        }
    }

    for (int m = 0; m < 4; m++) {
        int gm = tM + wM * 64 + m * 16 + quad * 4;
        for (int n = 0; n < 4; n++) {
            int gn = tN + wN * 64 + n * 16 + l15;
            int three = gn >> 10;
            int h = (gn >> 6) & 15;
            int dd = gn & 63;
            ushort_t* dst = (three == 0) ? outQ : (three == 1) ? outK : outV;
            for (int r = 0; r < 4; r++) {
                int row = gm + r;
                int b = row >> 11;
                int ns = row & 2047;
                dst[(((size_t)(b * 16 + h) * 2048 + ns) << 6) + dd] = f2bf(acc[m][n][r]);
            }
        }
    }
}

// ---------- flash attention (r6 measured-best): paired q-tiles, deferred softmax, K/V dbuf ----------
// q,k,v: [BH][N][d] bf16; out: [B][N][H*d] bf16
__global__ __launch_bounds__(256) void attn_kernel(
    const ushort_t* __restrict__ q, const ushort_t* __restrict__ k,
    const ushort_t* __restrict__ v, const int* __restrict__ pad,
    const int* __restrict__ csp, ushort_t* __restrict__ out) {
    __shared__ __align__(16) ushort_t Ks[2][64 * 64];    // [key][dd], XOR-swizzled
    __shared__ __align__(16) ushort_t VsT[2][64 * 64];   // [dd][key], XOR-swizzled
    __shared__ __align__(16) ushort_t Ps[4][2][16 * 64]; // per-wave, per-tile
    __shared__ float padb[2048];

    int cs = csp[0];
    int t = threadIdx.x, w = t >> 6, lane = t & 63;
    int quad = lane >> 4, l15 = lane & 15;
    int bh = blockIdx.y;
    int b = bh >> 4, h = bh & 15;
    int xp = blockIdx.x;
    int qtA = 31 - xp, qtB = xp;
    int q0A = qtA * 64, q0B = qtB * 64;
    const float c1 = 0.18033688f;    // 0.125 * log2(e)
    const float c2 = -11.541560f;    // -8 * log2(e)

    for (int i = 0; i < 8; i++) {
        int key = t + i * 256;
        padb[key] = pad[b * 2048 + key] ? -1e38f : c2;
    }

    const ushort_t* qbA = q + ((size_t)bh * 2048 + q0A + w * 16 + l15) * 64;
    short8 qA0 = *(const short8*)(qbA + quad * 8);
    short8 qA1 = *(const short8*)(qbA + 32 + quad * 8);
    const ushort_t* qbB = q + ((size_t)bh * 2048 + q0B + w * 16 + l15) * 64;
    short8 qB0 = *(const short8*)(qbB + quad * 8);
    short8 qB1 = *(const short8*)(qbB + 32 + quad * 8);

    float4_t OA[4], OB[4];
    for (int i = 0; i < 4; i++) { OA[i] = (float4_t){0.f,0.f,0.f,0.f}; OB[i] = (float4_t){0.f,0.f,0.f,0.f}; }
    float lsA[4] = {0.f,0.f,0.f,0.f}, lsB[4] = {0.f,0.f,0.f,0.f};

    int csT = (cs + 63) >> 6;
    int nTA = qtA + 1; if (csT > nTA) nTA = csT;
    int nTB = qtB + 1; if (csT > nTB) nTB = csT;
    int nTmax = nTA > nTB ? nTA : nTB;

    const ushort_t* kbase = k + (size_t)bh * 2048 * 64;
    const ushort_t* vbase = v + (size_t)bh * 2048 * 64;

    int lrow = lane >> 3, lblk = lane & 7;
    int prowA = q0A + w * 16 + quad * 4;
    int prowB = q0B + w * 16 + quad * 4;
    int sw = l15 & 7;

    short8 vr0, vr1;   // V register-prefetch
    auto stageK = [&](int it, int buf) {
        int k0 = it * 64;
        for (int i = 0; i < 2; i++) {
            int brow = w * 16 + i * 8;
            const ushort_t* gk = kbase + (size_t)(k0 + brow + lrow) * 64 + ((lblk ^ lrow) * 8);
            __builtin_amdgcn_global_load_lds((AS1 void*)gk, (AS3 void*)&Ks[buf][brow * 64], 16, 0, 0);
        }
    };
    auto loadV = [&](int it) {
        const ushort_t* vb = vbase + (size_t)(it * 64 + lane) * 64;
        vr0 = *(const short8*)(vb + w * 8);
        vr1 = *(const short8*)(vb + (w + 4) * 8);
    };

    stageK(0, 0);
    loadV(0);

    for (int it = 0; it < nTmax; it++) {
        int cur = it & 1, nxt = cur ^ 1;
        for (int j = 0; j < 8; j++) {
            int sl = (((lane >> 3) ^ j) * 8) + (lane & 7);
            VsT[cur][(w * 8 + j) * 64 + sl] = (ushort_t)vr0[j];
            VsT[cur][((w + 4) * 8 + j) * 64 + sl] = (ushort_t)vr1[j];
        }
        __syncthreads();  // drains this tile's K glds; VsT[cur] visible
        if (it + 1 < nTmax) {
            stageK(it + 1, nxt);
            loadV(it + 1);
        }

        int k0 = it * 64;
        bool actA = it < nTA, actB = it < nTB;

        short8 kf0[4], kf1[4];
        for (int ks = 0; ks < 4; ks++) {
            const ushort_t* krow = &Ks[cur][(ks * 16 + l15) * 64];
            kf0[ks] = *(const short8*)(krow + (quad ^ sw) * 8);
            kf1[ks] = *(const short8*)(krow + ((4 + quad) ^ sw) * 8);
        }

        if (actA) {
            float4_t s[4];
            for (int ks = 0; ks < 4; ks++) {
                float4_t a = (float4_t){0.f,0.f,0.f,0.f};
                a = __builtin_amdgcn_mfma_f32_16x16x32_bf16(qA0, kf0[ks], a, 0, 0, 0);
                a = __builtin_amdgcn_mfma_f32_16x16x32_bf16(qA1, kf1[ks], a, 0, 0, 0);
                s[ks] = a;
            }
            bool needC = (it >= qtA) && (k0 + 63 >= cs);
            for (int ks = 0; ks < 4; ks++) {
                int key = k0 + ks * 16 + l15;
                float add = padb[key];
                for (int r = 0; r < 4; r++) {
                    float arg = s[ks][r] * c1 + add;
                    if (needC && (key > prowA + r) && (key >= cs)) arg = -1e38f;
                    float p = __builtin_amdgcn_exp2f(arg);
                    lsA[r] += p;
                    int row = quad * 4 + r;
                    Ps[w][0][row * 64 + (((ks * 2 + (l15 >> 3)) ^ (row & 7)) * 8) + (l15 & 7)] = f2bf_trunc(p);
                }
            }
        }
        if (actB) {
            float4_t s[4];
            for (int ks = 0; ks < 4; ks++) {
                float4_t a = (float4_t){0.f,0.f,0.f,0.f};
                a = __builtin_amdgcn_mfma_f32_16x16x32_bf16(qB0, kf0[ks], a, 0, 0, 0);
                a = __builtin_amdgcn_mfma_f32_16x16x32_bf16(qB1, kf1[ks], a, 0, 0, 0);
                s[ks] = a;
            }
            bool needC = (it >= qtB) && (k0 + 63 >= cs);
            for (int ks = 0; ks < 4; ks++) {
                int key = k0 + ks * 16 + l15;
                float add = padb[key];
                for (int r = 0; r < 4; r++) {
                    float arg = s[ks][r] * c1 + add;
                    if (needC && (key > prowB + r) && (key >= cs)) arg = -1e38f;
                    float p = __builtin_amdgcn_exp2f(arg);
                    lsB[r] += p;
                    int row = quad * 4 + r;
                    Ps[w][1][row * 64 + (((ks * 2 + (l15 >> 3)) ^ (row & 7)) * 8) + (l15 & 7)] = f2bf_trunc(p);
                }
            }
        }

        short8 vf0[4], vf1[4];
        for (int n = 0; n < 4; n++) {
            const ushort_t* vrow = &VsT[cur][(n * 16 + l15) * 64];
            vf0[n] = *(const short8*)(vrow + (quad ^ sw) * 8);
            vf1[n] = *(const short8*)(vrow + ((4 + quad) ^ sw) * 8);
        }
        if (actA) {
            const ushort_t* prl = &Ps[w][0][l15 * 64];
            short8 pf0 = *(const short8*)(prl + (quad ^ sw) * 8);
            short8 pf1 = *(const short8*)(prl + ((4 + quad) ^ sw) * 8);
            for (int n = 0; n < 4; n++) {
                OA[n] = __builtin_amdgcn_mfma_f32_16x16x32_bf16(pf0, vf0[n], OA[n], 0, 0, 0);
                OA[n] = __builtin_amdgcn_mfma_f32_16x16x32_bf16(pf1, vf1[n], OA[n], 0, 0, 0);
            }
        }
        if (actB) {
            const ushort_t* prl = &Ps[w][1][l15 * 64];
            short8 pf0 = *(const short8*)(prl + (quad ^ sw) * 8);
            short8 pf1 = *(const short8*)(prl + ((4 + quad) ^ sw) * 8);
            for (int n = 0; n < 4; n++) {
                OB[n] = __builtin_amdgcn_mfma_f32_16x16x32_bf16(pf0, vf0[n], OB[n], 0, 0, 0);
                OB[n] = __builtin_amdgcn_mfma_f32_16x16x32_bf16(pf1, vf1[n], OB[n], 0, 0, 0);
            }
        }
    }

    for (int r = 0; r < 4; r++) {
        float l = lsA[r];
        l += __shfl_xor(l, 1, 64); l += __shfl_xor(l, 2, 64);
        l += __shfl_xor(l, 4, 64); l += __shfl_xor(l, 8, 64);
        float inv = l > 0.f ? 1.f / l : 0.f;
        int row = q0A + w * 16 + quad * 4 + r;
        size_t ob = ((size_t)b * 2048 + row) * 1024 + h * 64;
        for (int n = 0; n < 4; n++)
            out[ob + n * 16 + l15] = f2bf(OA[n][r] * inv);
    }
    for (int r = 0; r < 4; r++) {
        float l = lsB[r];
        l += __shfl_xor(l, 1, 64); l += __shfl_xor(l, 2, 64);
        l += __shfl_xor(l, 4, 64); l += __shfl_xor(l, 8, 64);
        float inv = l > 0.f ? 1.f / l : 0.f;
        int row = q0B + w * 16 + quad * 4 + r;
        size_t ob = ((size_t)b * 2048 + row) * 1024 + h * 64;
        for (int n = 0; n < 4; n++)
            out[ob + n * 16 + l15] = f2bf(OB[n][r] * inv);
    }
}

// ---------- GEMM2: out = ao @ wprojT^T + bias (bf16 A via glds, fp32 out) ----------
__global__ __launch_bounds__(256) void gemm_out_k(
    const ushort_t* __restrict__ A, const ushort_t* __restrict__ Bt,
    const float* __restrict__ bias, float* __restrict__ outC) {
    const int K = 1024, N = 1024;
    __shared__ __align__(16) ushort_t As[128 * 64];
    __shared__ __align__(16) ushort_t Bs[128 * 64];
    int t = threadIdx.x;
    int w = t >> 6, lane = t & 63;
    int quad = lane >> 4, l15 = lane & 15;
    int wM = w >> 1, wN = w & 1;
    int tM = blockIdx.y * 128, tN = blockIdx.x * 128;

    float4_t acc[4][4];
    for (int i = 0; i < 4; i++)
        for (int j = 0; j < 4; j++) acc[i][j] = (float4_t){0.f, 0.f, 0.f, 0.f};

    int lrow = lane >> 3;
    int lcol8 = (lane & 7) * 8;

    const ushort_t* Abase = A + (size_t)(tM + w * 32) * K;
    const ushort_t* Bbase = Bt + (size_t)(tN + w * 32) * K;

    for (int k0 = 0; k0 < K; k0 += 64) {
        __syncthreads();
        for (int i = 0; i < 4; i++) {
            const ushort_t* ga = Abase + (size_t)(i * 8 + lrow) * K + k0 + lcol8;
            __builtin_amdgcn_global_load_lds((AS1 void*)ga, (AS3 void*)&As[(w * 32 + i * 8) * 64], 16, 0, 0);
            const ushort_t* gb = Bbase + (size_t)(i * 8 + lrow) * K + k0 + lcol8;
            __builtin_amdgcn_global_load_lds((AS1 void*)gb, (AS3 void*)&Bs[(w * 32 + i * 8) * 64], 16, 0, 0);
        }
        __syncthreads();
        for (int kt = 0; kt < 2; kt++) {
            short8 af[4], bf[4];
            for (int m = 0; m < 4; m++)
                af[m] = *(const short8*)&As[(wM * 64 + m * 16 + l15) * 64 + kt * 32 + quad * 8];
            for (int n = 0; n < 4; n++)
                bf[n] = *(const short8*)&Bs[(wN * 64 + n * 16 + l15) * 64 + kt * 32 + quad * 8];
            for (int m = 0; m < 4; m++)
                for (int n = 0; n < 4; n++)
                    acc[m][n] = __builtin_amdgcn_mfma_f32_16x16x32_bf16(af[m], bf[n], acc[m][n], 0, 0, 0);
        }
    }

    for (int m = 0; m < 4; m++) {
        int gm = tM + wM * 64 + m * 16 + quad * 4;
        for (int n = 0; n < 4; n++) {
            int gn = tN + wN * 64 + n * 16 + l15;
            float bv = bias[gn];
            for (int r = 0; r < 4; r++)
                outC[(size_t)(gm + r) * N + gn] = acc[m][n][r] + bv;
        }
    }
}

extern "C" void kernel_launch(void* const* d_in, const int* in_sizes, int n_in,
                              void* d_out, int out_size, void* d_ws, size_t ws_size,
                              hipStream_t stream) {
    const float* x = (const float*)d_in[0];
    const int* pad = (const int*)d_in[1];
    const int* cs = (const int*)d_in[2];
    const float* wqkv = (const float*)d_in[3];
    const float* wproj = (const float*)d_in[4];
    const float* bproj = (const float*)d_in[5];
    float* out = (float*)d_out;

    // ws (peak 32 MB, lifetimes audited):
    //   q[0,8M) k[8,16M) v[16,24M)        gemm1 -> attn
    //   wqkvT[24,30M)                     prep -> gemm1 (dies)
    //   ao bf16 [24,32M)                  attn -> gemm2 (over dead wqkvT)
    //   wprojT[0,2M)                      transposed AFTER attn (over dead q)
    // d_out: xbf bf16 [0,8M) prep -> gemm1 (dies); final fp32 out from gemm2.
    ushort_t* ws = (ushort_t*)d_ws;
    ushort_t* qws = ws;
    ushort_t* kws = ws + (size_t)4194304;
    ushort_t* vws = ws + (size_t)8388608;
    ushort_t* wqkvT = ws + (size_t)12582912;
    ushort_t* aows = ws + (size_t)12582912;
    ushort_t* wprojT = ws;
    ushort_t* xbf = (ushort_t*)d_out;

    prep_fused<<<2816, 256, 0, stream>>>(wqkv, x, wqkvT, xbf);
    gemm_qkv<<<dim3(24, 32), 256, 0, stream>>>(xbf, wqkvT, qws, kws, vws);
    attn_kernel<<<dim3(16, 32), 256, 0, stream>>>(qws, kws, vws, pad, cs, aows);
    transpose_f32_bf16<<<dim3(16, 16), 256, 0, stream>>>(wproj, wprojT, 1024, 1024);
    gemm_out_k<<<dim3(8, 32), 256, 0, stream>>>(aows, wprojT, bproj, out);
}